// Round 12
// baseline (117.587 us; speedup 1.0000x reference)
//
#include <hip/hip_runtime.h>

// SemanticConditioner: out = canvas + (embeddings @ W^T + residuals)[region_ids]
// B=4, N=65536, D=256, E=1536, R=512  (all fp32)

#define B_DIM 4
#define N_DIM 65536
#define D_DIM 256
#define E_DIM 1536
#define R_DIM 512
#define RPB   8     // embedding rows per block (cond GEMM)
#define KS    8     // K-splits (cond GEMM)
#define KSUB  (E_DIM / KS)      // 192
#define KSUB4 (KSUB / 4)        // 48

typedef float f32x4 __attribute__((ext_vector_type(4)));

// ---------------------------------------------------------------------------
// Kernel 1: transpose W [D][E] -> Wt [E][D]
// grid (E/32, D/32) = (48, 8), 256 threads
// ---------------------------------------------------------------------------
__global__ __launch_bounds__(256) void k_transpose(const float* __restrict__ W,
                                                   float* __restrict__ Wt) {
    __shared__ float t[32][33];
    const int eb = blockIdx.x * 32;
    const int db = blockIdx.y * 32;
    const int tx = threadIdx.x & 31;
    const int ty = threadIdx.x >> 5;
#pragma unroll
    for (int j = 0; j < 4; ++j)
        t[ty + 8 * j][tx] = W[(size_t)(db + ty + 8 * j) * E_DIM + eb + tx];
    __syncthreads();
#pragma unroll
    for (int j = 0; j < 4; ++j)
        Wt[(size_t)(eb + ty + 8 * j) * D_DIM + db + tx] = t[tx][ty + 8 * j];
}

// ---------------------------------------------------------------------------
// Kernel 2: partial GEMM  part[ks][r][d] = sum_{e in ks-chunk} emb[r][e]*Wt[e][d]
// grid (R/RPB, KS) = (64, 8) = 512 blocks, 256 threads
// ---------------------------------------------------------------------------
__global__ __launch_bounds__(256) void k_cond_part(const float* __restrict__ emb,
                                                   const float* __restrict__ Wt,
                                                   float* __restrict__ part) {
    __shared__ f32x4 embs[RPB][KSUB4];  // 6 KB
    const int r0 = blockIdx.x * RPB;
    const int ks = blockIdx.y;
    const int d  = threadIdx.x;

    const f32x4* eg = reinterpret_cast<const f32x4*>(emb);
    for (int f = d; f < RPB * KSUB4; f += 256) {
        const int rr = f / KSUB4, gg = f % KSUB4;
        embs[rr][gg] = eg[(size_t)(r0 + rr) * (E_DIM / 4) + ks * KSUB4 + gg];
    }
    __syncthreads();

    float a0 = 0.f, a1 = 0.f, a2 = 0.f, a3 = 0.f;
    float a4 = 0.f, a5 = 0.f, a6 = 0.f, a7 = 0.f;
    const int ebase = ks * KSUB;
#pragma unroll 4
    for (int g = 0; g < KSUB4; ++g) {
        const int e = ebase + 4 * g;
        const float w0 = Wt[(size_t)(e + 0) * D_DIM + d];
        const float w1 = Wt[(size_t)(e + 1) * D_DIM + d];
        const float w2 = Wt[(size_t)(e + 2) * D_DIM + d];
        const float w3 = Wt[(size_t)(e + 3) * D_DIM + d];
        { const f32x4 v = embs[0][g]; a0 += v.x*w0 + v.y*w1 + v.z*w2 + v.w*w3; }
        { const f32x4 v = embs[1][g]; a1 += v.x*w0 + v.y*w1 + v.z*w2 + v.w*w3; }
        { const f32x4 v = embs[2][g]; a2 += v.x*w0 + v.y*w1 + v.z*w2 + v.w*w3; }
        { const f32x4 v = embs[3][g]; a3 += v.x*w0 + v.y*w1 + v.z*w2 + v.w*w3; }
        { const f32x4 v = embs[4][g]; a4 += v.x*w0 + v.y*w1 + v.z*w2 + v.w*w3; }
        { const f32x4 v = embs[5][g]; a5 += v.x*w0 + v.y*w1 + v.z*w2 + v.w*w3; }
        { const f32x4 v = embs[6][g]; a6 += v.x*w0 + v.y*w1 + v.z*w2 + v.w*w3; }
        { const f32x4 v = embs[7][g]; a7 += v.x*w0 + v.y*w1 + v.z*w2 + v.w*w3; }
    }
    float* p = part + ((size_t)ks * R_DIM + r0) * D_DIM + d;
    p[0 * D_DIM] = a0;
    p[1 * D_DIM] = a1;
    p[2 * D_DIM] = a2;
    p[3 * D_DIM] = a3;
    p[4 * D_DIM] = a4;
    p[5 * D_DIM] = a5;
    p[6 * D_DIM] = a6;
    p[7 * D_DIM] = a7;
}

// ---------------------------------------------------------------------------
// Kernel 3: cond[r][d] = sum_ks part[ks][r][d] + res[r][d]
// grid R*D/256 = 512 blocks, 256 threads
// ---------------------------------------------------------------------------
__global__ __launch_bounds__(256) void k_reduce(const float* __restrict__ part,
                                                const float* __restrict__ res,
                                                float* __restrict__ cond) {
    const int i = blockIdx.x * 256 + threadIdx.x;  // r*D + d
    const size_t stride = (size_t)R_DIM * D_DIM;
    float s = res[i];
#pragma unroll
    for (int ks = 0; ks < KS; ++ks)
        s += part[i + ks * stride];
    cond[i] = s;
}

// ---------------------------------------------------------------------------
// Kernel 4: out = canvas + cond[region_ids]
// A/B this round (single variable vs R11): b split across BLOCKS instead of
// within threads. 65536 blocks, ONE canvas load + ONE NT store per thread
// (minimal per-wave VMEM queue: rid + cond + canvas + store), 4x block pool,
// no more 4-stream same-offset bursts from a single wave. cond gather x4
// (proven ~free in R5); rid/cond still wave-uniform per n-row.
// Cached canvas loads (L3-resident) + NT stores (no-allocate).
// ---------------------------------------------------------------------------
__global__ __launch_bounds__(256) void k_add(const f32x4* __restrict__ canvas,
                                             const int* __restrict__ rid,
                                             const f32x4* __restrict__ cond,
                                             f32x4* __restrict__ out) {
    // grid.x = B*N*D/4 / 256 = 65536; i covers all of [B,N,D/4] flat
    const int i = blockIdx.x * blockDim.x + threadIdx.x;
    const int n  = (i >> 6) & (N_DIM - 1);   // wave-uniform
    const int d4 = i & 63;
    const f32x4 c = canvas[i];
    const int r  = rid[n];                   // wave-uniform, L1/L2
    const f32x4 a = cond[r * (D_DIM / 4) + d4];  // coalesced 1 KB row, L2
    __builtin_nontemporal_store(c + a, &out[i]);
}

// ---------------------------------------------------------------------------
extern "C" void kernel_launch(void* const* d_in, const int* in_sizes, int n_in,
                              void* d_out, int out_size, void* d_ws, size_t ws_size,
                              hipStream_t stream) {
    const float* canvas = (const float*)d_in[0];  // [B,N,D]
    const float* emb    = (const float*)d_in[1];  // [R,E]
    const float* W      = (const float*)d_in[2];  // [D,E]
    const float* res    = (const float*)d_in[3];  // [R,D]
    const int*   rid    = (const int*)d_in[4];    // [N]

    // ws layout: Wt (E*D) | part (KS*R*D) | cond (R*D)   -- all fp32
    float* Wt   = (float*)d_ws;
    float* part = Wt + (size_t)E_DIM * D_DIM;
    float* cond = part + (size_t)KS * R_DIM * D_DIM;

    dim3 tgrid(E_DIM / 32, D_DIM / 32);
    k_transpose<<<tgrid, 256, 0, stream>>>(W, Wt);
    dim3 cgrid(R_DIM / RPB, KS);
    k_cond_part<<<cgrid, 256, 0, stream>>>(emb, Wt, part);
    k_reduce<<<(R_DIM * D_DIM) / 256, 256, 0, stream>>>(part, res, cond);
    k_add<<<(B_DIM * N_DIM * (D_DIM / 4)) / 256, 256, 0, stream>>>(
        (const f32x4*)canvas, rid, (const f32x4*)cond, (f32x4*)d_out);
}

// Round 13
// 114.277 us; speedup vs baseline: 1.0290x; 1.0290x over previous
//
#include <hip/hip_runtime.h>

// SemanticConditioner: out = canvas + (embeddings @ W^T + residuals)[region_ids]
// B=4, N=65536, D=256, E=1536, R=512  (all fp32)

#define B_DIM 4
#define N_DIM 65536
#define D_DIM 256
#define E_DIM 1536
#define R_DIM 512
#define RPB   8     // embedding rows per block (cond GEMM)
#define KS    8     // K-splits (cond GEMM)
#define KSUB  (E_DIM / KS)      // 192
#define KSUB4 (KSUB / 4)        // 48

typedef float f32x4 __attribute__((ext_vector_type(4)));

// ---------------------------------------------------------------------------
// Kernel 1: partial GEMM, W read DIRECTLY (no transpose kernel, no Wt buffer).
// part[ks][r][d] = sum_{e in ks-chunk} emb[r][e] * W[d][e]
// Thread d reads its OWN contiguous W-row chunk as float4: W[d][e..e+3] ==
// old Wt[e..e+3][d]. Uncoalesced across lanes (64 lines/inst) but each 64B
// line feeds 4 consecutive float4 loads of the same thread -> 75% L1 hits;
// active set 256 rows x 64 B = 16 KB << 32 KB L1; W is L2-resident.
// grid (R/RPB, KS) = (64, 8) = 512 blocks, 256 threads
// ---------------------------------------------------------------------------
__global__ __launch_bounds__(256) void k_cond_direct(const float* __restrict__ emb,
                                                     const float* __restrict__ W,
                                                     float* __restrict__ part) {
    __shared__ f32x4 embs[RPB][KSUB4];  // 6 KB
    const int r0 = blockIdx.x * RPB;
    const int ks = blockIdx.y;
    const int d  = threadIdx.x;

    const f32x4* eg = reinterpret_cast<const f32x4*>(emb);
    for (int f = d; f < RPB * KSUB4; f += 256) {
        const int rr = f / KSUB4, gg = f % KSUB4;
        embs[rr][gg] = eg[(size_t)(r0 + rr) * (E_DIM / 4) + ks * KSUB4 + gg];
    }
    __syncthreads();

    float a0 = 0.f, a1 = 0.f, a2 = 0.f, a3 = 0.f;
    float a4 = 0.f, a5 = 0.f, a6 = 0.f, a7 = 0.f;
    // thread's own W-row chunk: W[d][ks*KSUB .. +KSUB), contiguous
    const f32x4* wrow =
        reinterpret_cast<const f32x4*>(W + (size_t)d * E_DIM + ks * KSUB);
#pragma unroll 4
    for (int g = 0; g < KSUB4; ++g) {
        const f32x4 w = wrow[g];          // one dwordx4 = old 4 scalar Wt loads
        const float w0 = w.x, w1 = w.y, w2 = w.z, w3 = w.w;
        { const f32x4 v = embs[0][g]; a0 += v.x*w0 + v.y*w1 + v.z*w2 + v.w*w3; }
        { const f32x4 v = embs[1][g]; a1 += v.x*w0 + v.y*w1 + v.z*w2 + v.w*w3; }
        { const f32x4 v = embs[2][g]; a2 += v.x*w0 + v.y*w1 + v.z*w2 + v.w*w3; }
        { const f32x4 v = embs[3][g]; a3 += v.x*w0 + v.y*w1 + v.z*w2 + v.w*w3; }
        { const f32x4 v = embs[4][g]; a4 += v.x*w0 + v.y*w1 + v.z*w2 + v.w*w3; }
        { const f32x4 v = embs[5][g]; a5 += v.x*w0 + v.y*w1 + v.z*w2 + v.w*w3; }
        { const f32x4 v = embs[6][g]; a6 += v.x*w0 + v.y*w1 + v.z*w2 + v.w*w3; }
        { const f32x4 v = embs[7][g]; a7 += v.x*w0 + v.y*w1 + v.z*w2 + v.w*w3; }
    }
    float* p = part + ((size_t)ks * R_DIM + r0) * D_DIM + d;
    p[0 * D_DIM] = a0;
    p[1 * D_DIM] = a1;
    p[2 * D_DIM] = a2;
    p[3 * D_DIM] = a3;
    p[4 * D_DIM] = a4;
    p[5 * D_DIM] = a5;
    p[6 * D_DIM] = a6;
    p[7 * D_DIM] = a7;
}

// ---------------------------------------------------------------------------
// Kernel 2: cond[r][d] = sum_ks part[ks][r][d] + res[r][d]
// grid R*D/256 = 512 blocks, 256 threads
// ---------------------------------------------------------------------------
__global__ __launch_bounds__(256) void k_reduce(const float* __restrict__ part,
                                                const float* __restrict__ res,
                                                float* __restrict__ cond) {
    const int i = blockIdx.x * 256 + threadIdx.x;  // r*D + d
    const size_t stride = (size_t)R_DIM * D_DIM;
    float s = res[i];
#pragma unroll
    for (int ks = 0; ks < KS; ++ks)
        s += part[i + ks * stride];
    cond[i] = s;
}

// ---------------------------------------------------------------------------
// Kernel 3: out = canvas + cond[region_ids]   — EXACT R11 winner (best: 115.8)
// 16384 blocks, one thread = one d4 across all B=4 batch rows (b-fused:
// 1 rid + 1 cond gather serve 4 canvas/out row triples).
// Cached canvas loads (L3 absorbs ~45% of reads) + NT stores (no-allocate).
// Block pool 16384 is the measured optimum (2048<8192<16384>65536).
// ---------------------------------------------------------------------------
__global__ __launch_bounds__(256) void k_add(const f32x4* __restrict__ canvas,
                                             const int* __restrict__ rid,
                                             const f32x4* __restrict__ cond,
                                             f32x4* __restrict__ out) {
    const int bstep = N_DIM * (D_DIM / 4);                  // 4,194,304 float4
    const int i = blockIdx.x * blockDim.x + threadIdx.x;    // n*64 + d4
    const f32x4 c0 = canvas[i];
    const f32x4 c1 = canvas[i + bstep];
    const f32x4 c2 = canvas[i + 2 * bstep];
    const f32x4 c3 = canvas[i + 3 * bstep];
    const int n  = i >> 6;              // wave-uniform
    const int d4 = i & 63;
    const int r  = rid[n];              // wave-uniform, L1/L2
    const f32x4 a = cond[r * (D_DIM / 4) + d4];  // coalesced 1 KB row, L2
    __builtin_nontemporal_store(c0 + a, &out[i]);
    __builtin_nontemporal_store(c1 + a, &out[i + bstep]);
    __builtin_nontemporal_store(c2 + a, &out[i + 2 * bstep]);
    __builtin_nontemporal_store(c3 + a, &out[i + 3 * bstep]);
}

// ---------------------------------------------------------------------------
extern "C" void kernel_launch(void* const* d_in, const int* in_sizes, int n_in,
                              void* d_out, int out_size, void* d_ws, size_t ws_size,
                              hipStream_t stream) {
    const float* canvas = (const float*)d_in[0];  // [B,N,D]
    const float* emb    = (const float*)d_in[1];  // [R,E]
    const float* W      = (const float*)d_in[2];  // [D,E]
    const float* res    = (const float*)d_in[3];  // [R,D]
    const int*   rid    = (const int*)d_in[4];    // [N]

    // ws layout: part (KS*R*D fp32 = 4 MB) | cond (R*D fp32 = 0.5 MB)
    float* part = (float*)d_ws;
    float* cond = part + (size_t)KS * R_DIM * D_DIM;

    dim3 cgrid(R_DIM / RPB, KS);
    k_cond_direct<<<cgrid, 256, 0, stream>>>(emb, W, part);
    k_reduce<<<(R_DIM * D_DIM) / 256, 256, 0, stream>>>(part, res, cond);
    k_add<<<16384, 256, 0, stream>>>((const f32x4*)canvas, rid,
                                     (const f32x4*)cond, (f32x4*)d_out);
}